// Round 4
// baseline (460.265 us; speedup 1.0000x reference)
//
#include <hip/hip_runtime.h>

#define EPSV 1e-5f
#define STATS_BLOCKS 512

// ---------------- degree histogram ----------------
__global__ void k_deg(const int* __restrict__ dst, int E, int* __restrict__ degc){
  int i = blockIdx.x*blockDim.x + threadIdx.x;
  if(i < E) atomicAdd(&degc[dst[i]], 1);
}

// ---------------- parallel scan: stage 1 (per-block exclusive scan) ----------------
__global__ __launch_bounds__(1024) void k_scan_local(const int* __restrict__ degc, int N,
                                                     int* __restrict__ loc, int* __restrict__ blk){
  __shared__ int ps[1024];
  int t = threadIdx.x;
  int i = blockIdx.x*1024 + t;
  int v = (i < N) ? degc[i] : 0;
  ps[t] = v;
  __syncthreads();
  for(int off=1; off<1024; off<<=1){
    int u = (t>=off) ? ps[t-off] : 0;
    __syncthreads();
    ps[t] += u;
    __syncthreads();
  }
  if(i < N) loc[i] = ps[t] - v;
  if(t == 1023) blk[blockIdx.x] = ps[t];
}

// ---------------- parallel scan: stage 2 (scan block sums) ----------------
__global__ __launch_bounds__(1024) void k_scan_sums(int* __restrict__ blk, int nb,
                                                    int* __restrict__ totalOut){
  __shared__ int ps[1024];
  int t = threadIdx.x;
  int v = (t < nb) ? blk[t] : 0;
  ps[t] = v;
  __syncthreads();
  for(int off=1; off<1024; off<<=1){
    int u = (t>=off) ? ps[t-off] : 0;
    __syncthreads();
    ps[t] += u;
    __syncthreads();
  }
  if(t < nb) blk[t] = ps[t] - v;
  if(t == 1023) *totalOut = ps[t];
}

// ---------------- parallel scan: stage 3 (add offsets; emit rp, cursor, dis) ----------------
__global__ void k_scan_add(const int* __restrict__ loc, const int* __restrict__ blk,
                           const int* __restrict__ degc, int N,
                           int* __restrict__ rp, int* __restrict__ cursor,
                           float* __restrict__ dis){
  int i = blockIdx.x*256 + threadIdx.x;
  if(i < N){
    int v = loc[i] + blk[i>>10];
    rp[i] = v; cursor[i] = v;
    dis[i] = rsqrtf((float)degc[i] + 1.0f);
  }
}

// ---------------- CSR fill (by dst): src index only ----------------
__global__ void k_fill(const int* __restrict__ src, const int* __restrict__ dst, int E,
                       int* cursor, int* __restrict__ csr_src){
  int e = blockIdx.x*256 + threadIdx.x;
  if(e >= E) return;
  int pos = atomicAdd(&cursor[dst[e]], 1);
  csr_src[pos] = src[e];
}

// ---------------- layer-1 GEMM: P = (x @ W1) * dis[row], [N,32]->[N,16] ----------------
__global__ __launch_bounds__(256) void k_gemm1(const float* __restrict__ x,
                                               const float* __restrict__ W,
                                               const float* __restrict__ dis,
                                               int N, float* __restrict__ out){
  __shared__ __align__(16) float Ws[32*16];
  int t = threadIdx.x;
  for(int i=t; i<32*16; i+=256) Ws[i] = W[i];
  __syncthreads();
  int row = blockIdx.x*256 + t;
  if(row >= N) return;
  const float4* xr = (const float4*)(x + (size_t)row*32);
  float acc[16];
  #pragma unroll
  for(int j=0;j<16;j++) acc[j]=0.f;
  #pragma unroll
  for(int k4=0;k4<8;k4++){
    float4 v = xr[k4];
    float vv[4] = {v.x, v.y, v.z, v.w};
    #pragma unroll
    for(int kk=0;kk<4;kk++){
      float h = vv[kk];
      const float* wr = &Ws[(k4*4+kk)*16];
      #pragma unroll
      for(int j=0;j<16;j++) acc[j] += h*wr[j];
    }
  }
  float d = dis[row];
  float4* o = (float4*)(out + (size_t)row*16);
  o[0] = make_float4(acc[0]*d,acc[1]*d,acc[2]*d,acc[3]*d);
  o[1] = make_float4(acc[4]*d,acc[5]*d,acc[6]*d,acc[7]*d);
  o[2] = make_float4(acc[8]*d,acc[9]*d,acc[10]*d,acc[11]*d);
  o[3] = make_float4(acc[12]*d,acc[13]*d,acc[14]*d,acc[15]*d);
}

// ---------------- tiled GEMM with fused input-BN and output dis-scale ----------------
// P = (BN(h) @ W) * dis[row];  BN applied as h*sc[k]+sh[k] on LDS staging.
template<int CIN>
__global__ __launch_bounds__(256) void k_gemm_t(const float* __restrict__ h,
                                                const float* __restrict__ W,
                                                const float* __restrict__ st,  // [sc[CIN], sh[CIN]]
                                                const float* __restrict__ dis,
                                                int N, float* __restrict__ out){
  __shared__ __align__(16) float hT[CIN][132];
  __shared__ __align__(16) float Ws[CIN*64];
  int t = threadIdx.x;
  int rowbase = blockIdx.x*128;
  #pragma unroll
  for(int i=0;i<CIN/2;i++){
    int idx = i*256 + t;
    int k = idx & (CIN-1);
    int r = idx / CIN;
    int row = rowbase + r;
    hT[k][r] = (row < N) ? h[(size_t)row*CIN + k]*st[k] + st[CIN+k] : 0.f;
  }
  for(int i=t; i<CIN*64; i+=256) Ws[i] = W[i];
  __syncthreads();

  int cg = t & 15, rg = t >> 4;
  float acc[8][4];
  #pragma unroll
  for(int r=0;r<8;r++)
    #pragma unroll
    for(int c=0;c<4;c++) acc[r][c]=0.f;

  for(int k=0;k<CIN;k++){
    float4 a0 = *(const float4*)&hT[k][rg*8];
    float4 a1 = *(const float4*)&hT[k][rg*8+4];
    float4 wv = *(const float4*)&Ws[k*64 + cg*4];
    float ar[8] = {a0.x,a0.y,a0.z,a0.w,a1.x,a1.y,a1.z,a1.w};
    float wc[4] = {wv.x,wv.y,wv.z,wv.w};
    #pragma unroll
    for(int r=0;r<8;r++)
      #pragma unroll
      for(int c=0;c<4;c++)
        acc[r][c] += ar[r]*wc[c];
  }
  #pragma unroll
  for(int r=0;r<8;r++){
    int row = rowbase + rg*8 + r;
    if(row < N){
      float d = dis[row];
      *(float4*)(out + (size_t)row*64 + cg*4) =
        make_float4(acc[r][0]*d,acc[r][1]*d,acc[r][2]*d,acc[r][3]*d);
    }
  }
}

// ---------------- gather: A = tanh(dis[n]*(P[n] + sum_edges P[s]) + bias) ----------------
template<int C>
__global__ __launch_bounds__(256) void k_gather(const int* __restrict__ rp,
    const int* __restrict__ csr_src,
    const float* __restrict__ dis, const float* __restrict__ P,
    const float* __restrict__ bias, int N, float* __restrict__ A){
  constexpr int GP = C/4;
  int idx = blockIdx.x*256 + threadIdx.x;
  if(idx >= N*GP) return;
  int n = idx / GP, g = idx % GP;
  int beg = rp[n], end = rp[n+1];
  float d = dis[n];
  float4 v  = *(const float4*)(P + (size_t)n*C + g*4);
  float4 bb = *(const float4*)(bias + g*4);
  float ax = v.x, ay = v.y, az = v.z, aw = v.w;
  float bx = 0.f, by = 0.f, bz = 0.f, bw = 0.f;

  int j = beg;
  for(; j+1 < end; j += 2){
    int s0 = csr_src[j], s1 = csr_src[j+1];
    float4 u0 = *(const float4*)(P + (size_t)s0*C + g*4);
    float4 u1 = *(const float4*)(P + (size_t)s1*C + g*4);
    ax += u0.x; ay += u0.y; az += u0.z; aw += u0.w;
    bx += u1.x; by += u1.y; bz += u1.z; bw += u1.w;
  }
  if(j < end){
    int s0 = csr_src[j];
    float4 u0 = *(const float4*)(P + (size_t)s0*C + g*4);
    ax += u0.x; ay += u0.y; az += u0.z; aw += u0.w;
  }
  float4 o;
  o.x = tanhf((ax + bx)*d + bb.x); o.y = tanhf((ay + by)*d + bb.y);
  o.z = tanhf((az + bz)*d + bb.z); o.w = tanhf((aw + bw)*d + bb.w);
  *(float4*)(A + (size_t)n*C + g*4) = o;
}

// ---------------- per-column partial sums ----------------
template<int C>
__global__ void k_stats(const float* __restrict__ A, int N, float* __restrict__ partials){
  int t = threadIdx.x;
  int total = N*C;
  int stride = STATS_BLOCKS*256;
  float s = 0.f, q = 0.f;
  for(int idx = blockIdx.x*256 + t; idx < total; idx += stride){
    float v = A[idx];
    s += v; q += v*v;
  }
  __shared__ float ls[256], lq[256];
  ls[t]=s; lq[t]=q;
  __syncthreads();
  if(t < C){
    float S=0.f, Q=0.f;
    #pragma unroll
    for(int g=0; g<256/C; g++){ S += ls[g*C+t]; Q += lq[g*C+t]; }
    partials[blockIdx.x*2*C + t]     = S;
    partials[blockIdx.x*2*C + C + t] = Q;
  }
}

// ---------------- finalize BN scale/shift ----------------
template<int C>
__global__ void k_bn_final(const float* __restrict__ partials,
                           const float* __restrict__ gw, const float* __restrict__ be,
                           float invN, float* __restrict__ stats){
  constexpr int CH = 1024/C;
  int t = threadIdx.x;
  int c = t % C, ch = t / C;
  float S=0.f, Q=0.f;
  for(int b=ch; b<STATS_BLOCKS; b+=CH){
    S += partials[b*2*C + c];
    Q += partials[b*2*C + C + c];
  }
  __shared__ float fs[1024], fq[1024];
  fs[t]=S; fq[t]=Q;
  __syncthreads();
  if(t < C){
    float St=fs[t], Qt=fq[t];
    for(int g=1; g<CH; g++){ St += fs[g*C+t]; Qt += fq[g*C+t]; }
    float m = St*invN;
    float var = fmaxf(Qt*invN - m*m, 0.f);
    float inv = rsqrtf(var + EPSV);
    float sc = gw[t]*inv;
    stats[t]   = sc;
    stats[C+t] = be[t] - m*sc;
  }
}

// ---------------- mean-pool per graph + linear head ----------------
__global__ __launch_bounds__(256) void k_pool(const float* __restrict__ A,
                                              const int* __restrict__ batch, int N,
                                              const float* __restrict__ Wc,
                                              const float* __restrict__ bc,
                                              float* __restrict__ out){
  int gId = blockIdx.x;
  int t = threadIdx.x;
  int lo=0, hi=N;
  while(lo<hi){ int mid=(lo+hi)>>1; if(batch[mid] < gId) lo=mid+1; else hi=mid; }
  int start = lo;
  lo=start; hi=N;
  while(lo<hi){ int mid=(lo+hi)>>1; if(batch[mid] < gId+1) lo=mid+1; else hi=mid; }
  int end = lo;

  int c = t & 63, rg = t >> 6;
  float s = 0.f;
  for(int r = start+rg; r < end; r += 4) s += A[(size_t)r*64 + c];
  __shared__ float ls[256];
  ls[t] = s;
  __syncthreads();
  if(t < 64){
    float tot = ls[t] + ls[64+t] + ls[128+t] + ls[192+t];
    float cnt = (float)(end - start);
    float mean = tot / fmaxf(cnt, 1.0f);
    float v = mean * Wc[t];
    #pragma unroll
    for(int o=32; o>0; o>>=1) v += __shfl_down(v, o, 64);
    if(t == 0) out[gId] = v + bc[0];
  }
}

// ---------------- host launch ----------------
extern "C" void kernel_launch(void* const* d_in, const int* in_sizes, int n_in,
                              void* d_out, int out_size, void* d_ws, size_t ws_size,
                              hipStream_t stream) {
  const float* x     = (const float*)d_in[0];
  const int*   ei    = (const int*)d_in[1];
  const int*   batch = (const int*)d_in[2];
  const float* W1 = (const float*)d_in[3];
  const float* b1 = (const float*)d_in[4];
  const float* g1 = (const float*)d_in[5];
  const float* be1= (const float*)d_in[6];
  const float* W2 = (const float*)d_in[7];
  const float* b2 = (const float*)d_in[8];
  const float* g2 = (const float*)d_in[9];
  const float* be2= (const float*)d_in[10];
  const float* W3 = (const float*)d_in[11];
  const float* b3 = (const float*)d_in[12];
  const float* Wc = (const float*)d_in[13];
  const float* bc = (const float*)d_in[14];

  int N = in_sizes[2];
  int E = in_sizes[1] / 2;
  int G = out_size;
  const int* srcp = ei;
  const int* dstp = ei + E;
  float* out = (float*)d_out;

  char* w = (char*)d_ws;
  float* A        = (float*)w; w += (size_t)N*64*4;
  float* Bb       = (float*)w; w += (size_t)N*64*4;
  float* dis      = (float*)w; w += (size_t)N*4;
  int*   degc     = (int*)w;   w += (size_t)N*4;
  int*   row_ptr  = (int*)w;   w += (size_t)(N+1)*4;
  int*   cursor   = (int*)w;   w += (size_t)N*4;
  int*   csr_src  = (int*)w;   w += (size_t)E*4;
  int*   scan_loc = (int*)w;   w += (size_t)N*4;
  int*   scan_blk = (int*)w;   w += 1024*4;
  float* partials = (float*)w; w += (size_t)STATS_BLOCKS*128*4;
  float* stats    = (float*)w; w += 512;

  auto cdiv = [](long long a, long long b){ return (int)((a+b-1)/b); };
  int nb = cdiv(N, 1024);

  // ---- CSR build (once, reused by all 3 layers) ----
  hipMemsetAsync(degc, 0, (size_t)N*4, stream);
  k_deg<<<cdiv(E,256),256,0,stream>>>(dstp, E, degc);
  k_scan_local<<<nb,1024,0,stream>>>(degc, N, scan_loc, scan_blk);
  k_scan_sums<<<1,1024,0,stream>>>(scan_blk, nb, row_ptr + N);
  k_scan_add<<<cdiv(N,256),256,0,stream>>>(scan_loc, scan_blk, degc, N, row_ptr, cursor, dis);
  k_fill<<<cdiv(E,256),256,0,stream>>>(srcp, dstp, E, cursor, csr_src);

  // ---- Layer 1: 32 -> 16 ----
  k_gemm1<<<cdiv(N,256),256,0,stream>>>(x, W1, dis, N, Bb);
  k_gather<16><<<cdiv((long long)N*4,256),256,0,stream>>>(row_ptr, csr_src, dis, Bb, b1, N, A);
  k_stats<16><<<STATS_BLOCKS,256,0,stream>>>(A, N, partials);
  k_bn_final<16><<<1,1024,0,stream>>>(partials, g1, be1, 1.0f/N, stats);

  // ---- Layer 2: 16 -> 64 (BN1 fused into GEMM staging) ----
  k_gemm_t<16><<<cdiv(N,128),256,0,stream>>>(A, W2, stats, dis, N, Bb);
  k_gather<64><<<cdiv((long long)N*16,256),256,0,stream>>>(row_ptr, csr_src, dis, Bb, b2, N, A);
  k_stats<64><<<STATS_BLOCKS,256,0,stream>>>(A, N, partials);
  k_bn_final<64><<<1,1024,0,stream>>>(partials, g2, be2, 1.0f/N, stats);

  // ---- Layer 3: 64 -> 64 (BN2 fused into GEMM staging) ----
  k_gemm_t<64><<<cdiv(N,128),256,0,stream>>>(A, W3, stats, dis, N, Bb);
  k_gather<64><<<cdiv((long long)N*16,256),256,0,stream>>>(row_ptr, csr_src, dis, Bb, b3, N, A);

  // ---- Pool + head ----
  k_pool<<<G,256,0,stream>>>(A, batch, N, Wc, bc, out);
}

// Round 5
// 315.716 us; speedup vs baseline: 1.4578x; 1.4578x over previous
//
#include <hip/hip_runtime.h>

#define EPSV 1e-5f
#define STATS_BLOCKS 512

// ---- f32 -> bf16 round-to-nearest-even ----
__device__ inline unsigned f2bf(float f){
  unsigned u = __float_as_uint(f);
  u += 0x7fffu + ((u>>16)&1u);
  return u>>16;
}
#define BF_LO(u) __uint_as_float((u)<<16)
#define BF_HI(u) __uint_as_float((u)&0xffff0000u)

// ---------------- degree histogram + per-edge rank ----------------
__global__ void k_degrank(const int* __restrict__ dst, int E,
                          int* __restrict__ degc, int* __restrict__ rank){
  int i = blockIdx.x*blockDim.x + threadIdx.x;
  if(i < E) rank[i] = atomicAdd(&degc[dst[i]], 1);
}

// ---------------- parallel scan: stage 1 ----------------
__global__ __launch_bounds__(1024) void k_scan_local(const int* __restrict__ degc, int N,
                                                     int* __restrict__ loc, int* __restrict__ blk){
  __shared__ int ps[1024];
  int t = threadIdx.x;
  int i = blockIdx.x*1024 + t;
  int v = (i < N) ? degc[i] : 0;
  ps[t] = v;
  __syncthreads();
  for(int off=1; off<1024; off<<=1){
    int u = (t>=off) ? ps[t-off] : 0;
    __syncthreads();
    ps[t] += u;
    __syncthreads();
  }
  if(i < N) loc[i] = ps[t] - v;
  if(t == 1023) blk[blockIdx.x] = ps[t];
}

// ---------------- parallel scan: stage 2 ----------------
__global__ __launch_bounds__(1024) void k_scan_sums(int* __restrict__ blk, int nb,
                                                    int* __restrict__ totalOut){
  __shared__ int ps[1024];
  int t = threadIdx.x;
  int v = (t < nb) ? blk[t] : 0;
  ps[t] = v;
  __syncthreads();
  for(int off=1; off<1024; off<<=1){
    int u = (t>=off) ? ps[t-off] : 0;
    __syncthreads();
    ps[t] += u;
    __syncthreads();
  }
  if(t < nb) blk[t] = ps[t] - v;
  if(t == 1023) *totalOut = ps[t];
}

// ---------------- parallel scan: stage 3 (emit rp, dis) ----------------
__global__ void k_scan_add(const int* __restrict__ loc, const int* __restrict__ blk,
                           const int* __restrict__ degc, int N,
                           int* __restrict__ rp, float* __restrict__ dis){
  int i = blockIdx.x*256 + threadIdx.x;
  if(i < N){
    rp[i] = loc[i] + blk[i>>10];
    dis[i] = rsqrtf((float)degc[i] + 1.0f);
  }
}

// ---------------- CSR fill: deterministic position, NO atomic ----------------
__global__ void k_fill2(const int* __restrict__ src, const int* __restrict__ dst,
                        const int* __restrict__ rank, const int* __restrict__ rp,
                        int E, int* __restrict__ csr_src){
  int e = blockIdx.x*256 + threadIdx.x;
  if(e >= E) return;
  csr_src[rp[dst[e]] + rank[e]] = src[e];
}

// ---------------- layer-1 GEMM: P = bf16((x @ W1) * dis[row]) ----------------
__global__ __launch_bounds__(256) void k_gemm1(const float* __restrict__ x,
                                               const float* __restrict__ W,
                                               const float* __restrict__ dis,
                                               int N, unsigned* __restrict__ Pu){
  __shared__ __align__(16) float Ws[32*16];
  int t = threadIdx.x;
  for(int i=t; i<32*16; i+=256) Ws[i] = W[i];
  __syncthreads();
  int row = blockIdx.x*256 + t;
  if(row >= N) return;
  const float4* xr = (const float4*)(x + (size_t)row*32);
  float acc[16];
  #pragma unroll
  for(int j=0;j<16;j++) acc[j]=0.f;
  #pragma unroll
  for(int k4=0;k4<8;k4++){
    float4 v = xr[k4];
    float vv[4] = {v.x, v.y, v.z, v.w};
    #pragma unroll
    for(int kk=0;kk<4;kk++){
      float h = vv[kk];
      const float* wr = &Ws[(k4*4+kk)*16];
      #pragma unroll
      for(int j=0;j<16;j++) acc[j] += h*wr[j];
    }
  }
  float d = dis[row];
  unsigned q[8];
  #pragma unroll
  for(int j=0;j<8;j++)
    q[j] = f2bf(acc[2*j]*d) | (f2bf(acc[2*j+1]*d)<<16);
  uint4* o = (uint4*)(Pu + (size_t)row*8);
  o[0] = make_uint4(q[0],q[1],q[2],q[3]);
  o[1] = make_uint4(q[4],q[5],q[6],q[7]);
}

// ---------------- tiled GEMM, fused input-BN, bf16 output ----------------
// P = bf16((BN(h) @ W) * dis[row])
template<int CIN>
__global__ __launch_bounds__(256) void k_gemm_t(const float* __restrict__ h,
                                                const float* __restrict__ W,
                                                const float* __restrict__ st,
                                                const float* __restrict__ dis,
                                                int N, unsigned* __restrict__ Pu){
  __shared__ __align__(16) float hT[CIN][132];
  __shared__ __align__(16) float Ws[CIN*64];
  int t = threadIdx.x;
  int rowbase = blockIdx.x*128;
  #pragma unroll
  for(int i=0;i<CIN/2;i++){
    int idx = i*256 + t;
    int k = idx & (CIN-1);
    int r = idx / CIN;
    int row = rowbase + r;
    hT[k][r] = (row < N) ? h[(size_t)row*CIN + k]*st[k] + st[CIN+k] : 0.f;
  }
  for(int i=t; i<CIN*64; i+=256) Ws[i] = W[i];
  __syncthreads();

  int cg = t & 15, rg = t >> 4;
  float acc[8][4];
  #pragma unroll
  for(int r=0;r<8;r++)
    #pragma unroll
    for(int c=0;c<4;c++) acc[r][c]=0.f;

  for(int k=0;k<CIN;k++){
    float4 a0 = *(const float4*)&hT[k][rg*8];
    float4 a1 = *(const float4*)&hT[k][rg*8+4];
    float4 wv = *(const float4*)&Ws[k*64 + cg*4];
    float ar[8] = {a0.x,a0.y,a0.z,a0.w,a1.x,a1.y,a1.z,a1.w};
    float wc[4] = {wv.x,wv.y,wv.z,wv.w};
    #pragma unroll
    for(int r=0;r<8;r++)
      #pragma unroll
      for(int c=0;c<4;c++)
        acc[r][c] += ar[r]*wc[c];
  }
  #pragma unroll
  for(int r=0;r<8;r++){
    int row = rowbase + rg*8 + r;
    if(row < N){
      float d = dis[row];
      unsigned p0 = f2bf(acc[r][0]*d) | (f2bf(acc[r][1]*d)<<16);
      unsigned p1 = f2bf(acc[r][2]*d) | (f2bf(acc[r][3]*d)<<16);
      *(uint2*)(Pu + (size_t)row*32 + cg*2) = make_uint2(p0,p1);
    }
  }
}

// ---------------- gather: A = tanh(dis[n]*(P[n] + sum P[s]) + bias), P bf16 ----------------
// thread = (node, 8-col group); reads 16B (8 bf16) per source row per lane.
template<int C>
__global__ __launch_bounds__(256) void k_gather(const int* __restrict__ rp,
    const int* __restrict__ csr_src,
    const float* __restrict__ dis, const unsigned* __restrict__ Pu,
    const float* __restrict__ bias, int N, float* __restrict__ A){
  constexpr int GP = C/8;
  int idx = blockIdx.x*256 + threadIdx.x;
  if(idx >= N*GP) return;
  int n = idx / GP, g = idx % GP;
  int beg = rp[n], end = rp[n+1];
  const uint4* Pv = (const uint4*)Pu;

  uint4 u = Pv[(size_t)n*GP + g];   // self row
  float a0 = BF_LO(u.x), a1 = BF_HI(u.x), a2 = BF_LO(u.y), a3 = BF_HI(u.y);
  float a4 = BF_LO(u.z), a5 = BF_HI(u.z), a6 = BF_LO(u.w), a7 = BF_HI(u.w);
  float b0=0.f,b1=0.f,b2=0.f,b3=0.f,b4=0.f,b5=0.f,b6=0.f,b7=0.f;

  int j = beg;
  for(; j+1 < end; j += 2){
    int s0 = csr_src[j], s1 = csr_src[j+1];
    uint4 u0 = Pv[(size_t)s0*GP + g];
    uint4 u1 = Pv[(size_t)s1*GP + g];
    a0 += BF_LO(u0.x); a1 += BF_HI(u0.x); a2 += BF_LO(u0.y); a3 += BF_HI(u0.y);
    a4 += BF_LO(u0.z); a5 += BF_HI(u0.z); a6 += BF_LO(u0.w); a7 += BF_HI(u0.w);
    b0 += BF_LO(u1.x); b1 += BF_HI(u1.x); b2 += BF_LO(u1.y); b3 += BF_HI(u1.y);
    b4 += BF_LO(u1.z); b5 += BF_HI(u1.z); b6 += BF_LO(u1.w); b7 += BF_HI(u1.w);
  }
  if(j < end){
    int s0 = csr_src[j];
    uint4 u0 = Pv[(size_t)s0*GP + g];
    a0 += BF_LO(u0.x); a1 += BF_HI(u0.x); a2 += BF_LO(u0.y); a3 += BF_HI(u0.y);
    a4 += BF_LO(u0.z); a5 += BF_HI(u0.z); a6 += BF_LO(u0.w); a7 += BF_HI(u0.w);
  }
  float d = dis[n];
  float4 bb0 = *(const float4*)(bias + g*8);
  float4 bb1 = *(const float4*)(bias + g*8 + 4);
  float4 o0, o1;
  o0.x = tanhf((a0+b0)*d + bb0.x); o0.y = tanhf((a1+b1)*d + bb0.y);
  o0.z = tanhf((a2+b2)*d + bb0.z); o0.w = tanhf((a3+b3)*d + bb0.w);
  o1.x = tanhf((a4+b4)*d + bb1.x); o1.y = tanhf((a5+b5)*d + bb1.y);
  o1.z = tanhf((a6+b6)*d + bb1.z); o1.w = tanhf((a7+b7)*d + bb1.w);
  float* ap = A + (size_t)n*C + g*8;
  *(float4*)ap = o0;
  *(float4*)(ap+4) = o1;
}

// ---------------- per-column partial sums ----------------
template<int C>
__global__ void k_stats(const float* __restrict__ A, int N, float* __restrict__ partials){
  int t = threadIdx.x;
  int total = N*C;
  int stride = STATS_BLOCKS*256;
  float s = 0.f, q = 0.f;
  for(int idx = blockIdx.x*256 + t; idx < total; idx += stride){
    float v = A[idx];
    s += v; q += v*v;
  }
  __shared__ float ls[256], lq[256];
  ls[t]=s; lq[t]=q;
  __syncthreads();
  if(t < C){
    float S=0.f, Q=0.f;
    #pragma unroll
    for(int g=0; g<256/C; g++){ S += ls[g*C+t]; Q += lq[g*C+t]; }
    partials[blockIdx.x*2*C + t]     = S;
    partials[blockIdx.x*2*C + C + t] = Q;
  }
}

// ---------------- finalize BN scale/shift ----------------
template<int C>
__global__ void k_bn_final(const float* __restrict__ partials,
                           const float* __restrict__ gw, const float* __restrict__ be,
                           float invN, float* __restrict__ stats){
  constexpr int CH = 1024/C;
  int t = threadIdx.x;
  int c = t % C, ch = t / C;
  float S=0.f, Q=0.f;
  for(int b=ch; b<STATS_BLOCKS; b+=CH){
    S += partials[b*2*C + c];
    Q += partials[b*2*C + C + c];
  }
  __shared__ float fs[1024], fq[1024];
  fs[t]=S; fq[t]=Q;
  __syncthreads();
  if(t < C){
    float St=fs[t], Qt=fq[t];
    for(int g=1; g<CH; g++){ St += fs[g*C+t]; Qt += fq[g*C+t]; }
    float m = St*invN;
    float var = fmaxf(Qt*invN - m*m, 0.f);
    float inv = rsqrtf(var + EPSV);
    float sc = gw[t]*inv;
    stats[t]   = sc;
    stats[C+t] = be[t] - m*sc;
  }
}

// ---------------- mean-pool per graph + linear head ----------------
__global__ __launch_bounds__(256) void k_pool(const float* __restrict__ A,
                                              const int* __restrict__ batch, int N,
                                              const float* __restrict__ Wc,
                                              const float* __restrict__ bc,
                                              float* __restrict__ out){
  int gId = blockIdx.x;
  int t = threadIdx.x;
  int lo=0, hi=N;
  while(lo<hi){ int mid=(lo+hi)>>1; if(batch[mid] < gId) lo=mid+1; else hi=mid; }
  int start = lo;
  lo=start; hi=N;
  while(lo<hi){ int mid=(lo+hi)>>1; if(batch[mid] < gId+1) lo=mid+1; else hi=mid; }
  int end = lo;

  int c = t & 63, rg = t >> 6;
  float s = 0.f;
  for(int r = start+rg; r < end; r += 4) s += A[(size_t)r*64 + c];
  __shared__ float ls[256];
  ls[t] = s;
  __syncthreads();
  if(t < 64){
    float tot = ls[t] + ls[64+t] + ls[128+t] + ls[192+t];
    float cnt = (float)(end - start);
    float mean = tot / fmaxf(cnt, 1.0f);
    float v = mean * Wc[t];
    #pragma unroll
    for(int o=32; o>0; o>>=1) v += __shfl_down(v, o, 64);
    if(t == 0) out[gId] = v + bc[0];
  }
}

// ---------------- host launch ----------------
extern "C" void kernel_launch(void* const* d_in, const int* in_sizes, int n_in,
                              void* d_out, int out_size, void* d_ws, size_t ws_size,
                              hipStream_t stream) {
  const float* x     = (const float*)d_in[0];
  const int*   ei    = (const int*)d_in[1];
  const int*   batch = (const int*)d_in[2];
  const float* W1 = (const float*)d_in[3];
  const float* b1 = (const float*)d_in[4];
  const float* g1 = (const float*)d_in[5];
  const float* be1= (const float*)d_in[6];
  const float* W2 = (const float*)d_in[7];
  const float* b2 = (const float*)d_in[8];
  const float* g2 = (const float*)d_in[9];
  const float* be2= (const float*)d_in[10];
  const float* W3 = (const float*)d_in[11];
  const float* b3 = (const float*)d_in[12];
  const float* Wc = (const float*)d_in[13];
  const float* bc = (const float*)d_in[14];

  int N = in_sizes[2];
  int E = in_sizes[1] / 2;
  int G = out_size;
  const int* srcp = ei;
  const int* dstp = ei + E;
  float* out = (float*)d_out;

  char* w = (char*)d_ws;
  float*    A        = (float*)w;    w += (size_t)N*64*4;
  unsigned* Pu       = (unsigned*)w; w += (size_t)N*32*4;   // bf16 P, N x 64
  float*    dis      = (float*)w;    w += (size_t)N*4;
  int*      degc     = (int*)w;      w += (size_t)N*4;
  int*      row_ptr  = (int*)w;      w += (size_t)(N+1)*4;
  int*      rank     = (int*)w;      w += (size_t)E*4;
  int*      csr_src  = (int*)w;      w += (size_t)E*4;
  int*      scan_loc = (int*)w;      w += (size_t)N*4;
  int*      scan_blk = (int*)w;      w += 1024*4;
  float*    partials = (float*)w;    w += (size_t)STATS_BLOCKS*128*4;
  float*    stats    = (float*)w;    w += 512;

  auto cdiv = [](long long a, long long b){ return (int)((a+b-1)/b); };
  int nb = cdiv(N, 1024);

  // ---- CSR build (once, reused by all 3 layers) ----
  hipMemsetAsync(degc, 0, (size_t)N*4, stream);
  k_degrank<<<cdiv(E,256),256,0,stream>>>(dstp, E, degc, rank);
  k_scan_local<<<nb,1024,0,stream>>>(degc, N, scan_loc, scan_blk);
  k_scan_sums<<<1,1024,0,stream>>>(scan_blk, nb, row_ptr + N);
  k_scan_add<<<cdiv(N,256),256,0,stream>>>(scan_loc, scan_blk, degc, N, row_ptr, dis);
  k_fill2<<<cdiv(E,256),256,0,stream>>>(srcp, dstp, rank, row_ptr, E, csr_src);

  // ---- Layer 1: 32 -> 16 ----
  k_gemm1<<<cdiv(N,256),256,0,stream>>>(x, W1, dis, N, Pu);
  k_gather<16><<<cdiv((long long)N*2,256),256,0,stream>>>(row_ptr, csr_src, dis, Pu, b1, N, A);
  k_stats<16><<<STATS_BLOCKS,256,0,stream>>>(A, N, partials);
  k_bn_final<16><<<1,1024,0,stream>>>(partials, g1, be1, 1.0f/N, stats);

  // ---- Layer 2: 16 -> 64 (BN1 fused into GEMM staging) ----
  k_gemm_t<16><<<cdiv(N,128),256,0,stream>>>(A, W2, stats, dis, N, Pu);
  k_gather<64><<<cdiv((long long)N*8,256),256,0,stream>>>(row_ptr, csr_src, dis, Pu, b2, N, A);
  k_stats<64><<<STATS_BLOCKS,256,0,stream>>>(A, N, partials);
  k_bn_final<64><<<1,1024,0,stream>>>(partials, g2, be2, 1.0f/N, stats);

  // ---- Layer 3: 64 -> 64 (BN2 fused into GEMM staging) ----
  k_gemm_t<64><<<cdiv(N,128),256,0,stream>>>(A, W3, stats, dis, N, Pu);
  k_gather<64><<<cdiv((long long)N*8,256),256,0,stream>>>(row_ptr, csr_src, dis, Pu, b3, N, A);

  // ---- Pool + head ----
  k_pool<<<G,256,0,stream>>>(A, batch, N, Wc, bc, out);
}

// Round 6
// 261.255 us; speedup vs baseline: 1.7617x; 1.2085x over previous
//
#include <hip/hip_runtime.h>

#define EPSV 1e-5f
#define STATS_BLOCKS 512
#define EB 512            // edge-chunk blocks for counting-sort passes
#define NPB 256           // nodes per bucket (bucket = dst >> 8)
#define NBUK_MAX 512      // supports N up to 131072

// ---- f32 -> bf16 round-to-nearest-even ----
__device__ inline unsigned f2bf(float f){
  unsigned u = __float_as_uint(f);
  u += 0x7fffu + ((u>>16)&1u);
  return u>>16;
}
#define BF_LO(u) __uint_as_float((u)<<16)
#define BF_HI(u) __uint_as_float((u)&0xffff0000u)

// ---------------- CSR build pass A: per-chunk bucket histograms (LDS atomics only) ----------------
__global__ __launch_bounds__(256) void k_csr_count(const int* __restrict__ dst, int E, int chunk,
                                                   int nbuk, int* __restrict__ cnt){
  __shared__ int hist[NBUK_MAX];
  int t = threadIdx.x, b = blockIdx.x;
  for(int k=t; k<nbuk; k+=256) hist[k]=0;
  __syncthreads();
  int lo = b*chunk, hi = lo+chunk < E ? lo+chunk : E;
  for(int i=lo+t; i<hi; i+=256) atomicAdd(&hist[dst[i]>>8], 1);
  __syncthreads();
  for(int k=t; k<nbuk; k+=256) cnt[(size_t)k*EB + b] = hist[k];
}

// ---------------- parallel scan: stage 1 ----------------
__global__ __launch_bounds__(1024) void k_scan_local(const int* __restrict__ v_in, int L,
                                                     int* __restrict__ loc, int* __restrict__ blk){
  __shared__ int ps[1024];
  int t = threadIdx.x;
  int i = blockIdx.x*1024 + t;
  int v = (i < L) ? v_in[i] : 0;
  ps[t] = v;
  __syncthreads();
  for(int off=1; off<1024; off<<=1){
    int u = (t>=off) ? ps[t-off] : 0;
    __syncthreads();
    ps[t] += u;
    __syncthreads();
  }
  if(i < L) loc[i] = ps[t] - v;
  if(t == 1023) blk[blockIdx.x] = ps[t];
}

// ---------------- parallel scan: stage 2 ----------------
__global__ __launch_bounds__(1024) void k_scan_sums(int* __restrict__ blk, int nb,
                                                    int* __restrict__ totalOut){
  __shared__ int ps[1024];
  int t = threadIdx.x;
  int v = (t < nb) ? blk[t] : 0;
  ps[t] = v;
  __syncthreads();
  for(int off=1; off<1024; off<<=1){
    int u = (t>=off) ? ps[t-off] : 0;
    __syncthreads();
    ps[t] += u;
    __syncthreads();
  }
  if(t < nb) blk[t] = ps[t] - v;
  if(t == 1023) *totalOut = ps[t];
}

// ---------------- parallel scan: stage 3 (emit exclusive positions) ----------------
__global__ void k_scan_add2(const int* __restrict__ loc, const int* __restrict__ blk, int L,
                            int* __restrict__ pos){
  int i = blockIdx.x*256 + threadIdx.x;
  if(i < L) pos[i] = loc[i] + blk[i>>10];
}

// ---------------- CSR build pass C: bucket-sort edges (LDS cursors only) ----------------
__global__ __launch_bounds__(256) void k_csr_scatter(const int* __restrict__ src,
                                                     const int* __restrict__ dst,
                                                     const int* __restrict__ pos, int E, int chunk,
                                                     int nbuk, uint2* __restrict__ ebuf){
  __shared__ int cur[NBUK_MAX];
  int t = threadIdx.x, b = blockIdx.x;
  for(int k=t; k<nbuk; k+=256) cur[k] = pos[(size_t)k*EB + b];
  __syncthreads();
  int lo = b*chunk, hi = lo+chunk < E ? lo+chunk : E;
  for(int i=lo+t; i<hi; i+=256){
    int d = dst[i];
    int p = atomicAdd(&cur[d>>8], 1);
    ebuf[p] = make_uint2((unsigned)src[i], (unsigned)d);
  }
}

// ---------------- CSR build pass D: per-bucket finalize (rp, dis, csr_src) ----------------
__global__ __launch_bounds__(256) void k_csr_final(const uint2* __restrict__ ebuf,
                                                   const int* __restrict__ pos,
                                                   int nbuk, int N, int E,
                                                   int* __restrict__ rp, float* __restrict__ dis,
                                                   int* __restrict__ csr_src){
  __shared__ int hist[NPB], ps[NPB], cur[NPB];
  int t = threadIdx.x, k = blockIdx.x;
  int base = pos[(size_t)k*EB];
  int next = (k+1 < nbuk) ? pos[(size_t)(k+1)*EB] : E;
  int cntk = next - base;
  int node0 = k*NPB;
  hist[t] = 0;
  __syncthreads();
  for(int i=t; i<cntk; i+=256) atomicAdd(&hist[(int)ebuf[base+i].y - node0], 1);
  __syncthreads();
  int deg = hist[t];
  ps[t] = deg;
  __syncthreads();
  for(int off=1; off<256; off<<=1){
    int u = (t>=off) ? ps[t-off] : 0;
    __syncthreads();
    ps[t] += u;
    __syncthreads();
  }
  int lb = ps[t] - deg;      // exclusive prefix within bucket
  int n = node0 + t;
  if(n < N){
    rp[n]  = base + lb;
    dis[n] = rsqrtf((float)deg + 1.0f);
  }
  cur[t] = base + lb;
  __syncthreads();
  for(int i=t; i<cntk; i+=256){
    uint2 e = ebuf[base+i];
    int p = atomicAdd(&cur[(int)e.y - node0], 1);
    csr_src[p] = (int)e.x;
  }
  if(k == nbuk-1 && t == 0) rp[N] = E;
}

// ---------------- layer-1 GEMM: P = bf16((x @ W1) * dis[row]) ----------------
__global__ __launch_bounds__(256) void k_gemm1(const float* __restrict__ x,
                                               const float* __restrict__ W,
                                               const float* __restrict__ dis,
                                               int N, unsigned* __restrict__ Pu){
  __shared__ __align__(16) float Ws[32*16];
  int t = threadIdx.x;
  for(int i=t; i<32*16; i+=256) Ws[i] = W[i];
  __syncthreads();
  int row = blockIdx.x*256 + t;
  if(row >= N) return;
  const float4* xr = (const float4*)(x + (size_t)row*32);
  float acc[16];
  #pragma unroll
  for(int j=0;j<16;j++) acc[j]=0.f;
  #pragma unroll
  for(int k4=0;k4<8;k4++){
    float4 v = xr[k4];
    float vv[4] = {v.x, v.y, v.z, v.w};
    #pragma unroll
    for(int kk=0;kk<4;kk++){
      float h = vv[kk];
      const float* wr = &Ws[(k4*4+kk)*16];
      #pragma unroll
      for(int j=0;j<16;j++) acc[j] += h*wr[j];
    }
  }
  float d = dis[row];
  unsigned q[8];
  #pragma unroll
  for(int j=0;j<8;j++)
    q[j] = f2bf(acc[2*j]*d) | (f2bf(acc[2*j+1]*d)<<16);
  uint4* o = (uint4*)(Pu + (size_t)row*8);
  o[0] = make_uint4(q[0],q[1],q[2],q[3]);
  o[1] = make_uint4(q[4],q[5],q[6],q[7]);
}

// ---------------- tiled GEMM, fused input-BN, bf16 output ----------------
template<int CIN>
__global__ __launch_bounds__(256) void k_gemm_t(const float* __restrict__ h,
                                                const float* __restrict__ W,
                                                const float* __restrict__ st,
                                                const float* __restrict__ dis,
                                                int N, unsigned* __restrict__ Pu){
  __shared__ __align__(16) float hT[CIN][132];
  __shared__ __align__(16) float Ws[CIN*64];
  int t = threadIdx.x;
  int rowbase = blockIdx.x*128;
  #pragma unroll
  for(int i=0;i<CIN/2;i++){
    int idx = i*256 + t;
    int k = idx & (CIN-1);
    int r = idx / CIN;
    int row = rowbase + r;
    hT[k][r] = (row < N) ? h[(size_t)row*CIN + k]*st[k] + st[CIN+k] : 0.f;
  }
  for(int i=t; i<CIN*64; i+=256) Ws[i] = W[i];
  __syncthreads();

  int cg = t & 15, rg = t >> 4;
  float acc[8][4];
  #pragma unroll
  for(int r=0;r<8;r++)
    #pragma unroll
    for(int c=0;c<4;c++) acc[r][c]=0.f;

  for(int k=0;k<CIN;k++){
    float4 a0 = *(const float4*)&hT[k][rg*8];
    float4 a1 = *(const float4*)&hT[k][rg*8+4];
    float4 wv = *(const float4*)&Ws[k*64 + cg*4];
    float ar[8] = {a0.x,a0.y,a0.z,a0.w,a1.x,a1.y,a1.z,a1.w};
    float wc[4] = {wv.x,wv.y,wv.z,wv.w};
    #pragma unroll
    for(int r=0;r<8;r++)
      #pragma unroll
      for(int c=0;c<4;c++)
        acc[r][c] += ar[r]*wc[c];
  }
  #pragma unroll
  for(int r=0;r<8;r++){
    int row = rowbase + rg*8 + r;
    if(row < N){
      float d = dis[row];
      unsigned p0 = f2bf(acc[r][0]*d) | (f2bf(acc[r][1]*d)<<16);
      unsigned p1 = f2bf(acc[r][2]*d) | (f2bf(acc[r][3]*d)<<16);
      *(uint2*)(Pu + (size_t)row*32 + cg*2) = make_uint2(p0,p1);
    }
  }
}

// ---------------- gather: A = tanh(dis[n]*(P[n] + sum P[s]) + bias), P bf16 ----------------
template<int C>
__global__ __launch_bounds__(256) void k_gather(const int* __restrict__ rp,
    const int* __restrict__ csr_src,
    const float* __restrict__ dis, const unsigned* __restrict__ Pu,
    const float* __restrict__ bias, int N, float* __restrict__ A){
  constexpr int GP = C/8;
  int idx = blockIdx.x*256 + threadIdx.x;
  if(idx >= N*GP) return;
  int n = idx / GP, g = idx % GP;
  int beg = rp[n], end = rp[n+1];
  const uint4* Pv = (const uint4*)Pu;

  uint4 u = Pv[(size_t)n*GP + g];   // self row
  float a0 = BF_LO(u.x), a1 = BF_HI(u.x), a2 = BF_LO(u.y), a3 = BF_HI(u.y);
  float a4 = BF_LO(u.z), a5 = BF_HI(u.z), a6 = BF_LO(u.w), a7 = BF_HI(u.w);
  float b0=0.f,b1=0.f,b2=0.f,b3=0.f,b4=0.f,b5=0.f,b6=0.f,b7=0.f;

  int j = beg;
  for(; j+1 < end; j += 2){
    int s0 = csr_src[j], s1 = csr_src[j+1];
    uint4 u0 = Pv[(size_t)s0*GP + g];
    uint4 u1 = Pv[(size_t)s1*GP + g];
    a0 += BF_LO(u0.x); a1 += BF_HI(u0.x); a2 += BF_LO(u0.y); a3 += BF_HI(u0.y);
    a4 += BF_LO(u0.z); a5 += BF_HI(u0.z); a6 += BF_LO(u0.w); a7 += BF_HI(u0.w);
    b0 += BF_LO(u1.x); b1 += BF_HI(u1.x); b2 += BF_LO(u1.y); b3 += BF_HI(u1.y);
    b4 += BF_LO(u1.z); b5 += BF_HI(u1.z); b6 += BF_LO(u1.w); b7 += BF_HI(u1.w);
  }
  if(j < end){
    int s0 = csr_src[j];
    uint4 u0 = Pv[(size_t)s0*GP + g];
    a0 += BF_LO(u0.x); a1 += BF_HI(u0.x); a2 += BF_LO(u0.y); a3 += BF_HI(u0.y);
    a4 += BF_LO(u0.z); a5 += BF_HI(u0.z); a6 += BF_LO(u0.w); a7 += BF_HI(u0.w);
  }
  float d = dis[n];
  float4 bb0 = *(const float4*)(bias + g*8);
  float4 bb1 = *(const float4*)(bias + g*8 + 4);
  float4 o0, o1;
  o0.x = tanhf((a0+b0)*d + bb0.x); o0.y = tanhf((a1+b1)*d + bb0.y);
  o0.z = tanhf((a2+b2)*d + bb0.z); o0.w = tanhf((a3+b3)*d + bb0.w);
  o1.x = tanhf((a4+b4)*d + bb1.x); o1.y = tanhf((a5+b5)*d + bb1.y);
  o1.z = tanhf((a6+b6)*d + bb1.z); o1.w = tanhf((a7+b7)*d + bb1.w);
  float* ap = A + (size_t)n*C + g*8;
  *(float4*)ap = o0;
  *(float4*)(ap+4) = o1;
}

// ---------------- per-column partial sums ----------------
template<int C>
__global__ void k_stats(const float* __restrict__ A, int N, float* __restrict__ partials){
  int t = threadIdx.x;
  int total = N*C;
  int stride = STATS_BLOCKS*256;
  float s = 0.f, q = 0.f;
  for(int idx = blockIdx.x*256 + t; idx < total; idx += stride){
    float v = A[idx];
    s += v; q += v*v;
  }
  __shared__ float ls[256], lq[256];
  ls[t]=s; lq[t]=q;
  __syncthreads();
  if(t < C){
    float S=0.f, Q=0.f;
    #pragma unroll
    for(int g=0; g<256/C; g++){ S += ls[g*C+t]; Q += lq[g*C+t]; }
    partials[blockIdx.x*2*C + t]     = S;
    partials[blockIdx.x*2*C + C + t] = Q;
  }
}

// ---------------- finalize BN scale/shift ----------------
template<int C>
__global__ void k_bn_final(const float* __restrict__ partials,
                           const float* __restrict__ gw, const float* __restrict__ be,
                           float invN, float* __restrict__ stats){
  constexpr int CH = 1024/C;
  int t = threadIdx.x;
  int c = t % C, ch = t / C;
  float S=0.f, Q=0.f;
  for(int b=ch; b<STATS_BLOCKS; b+=CH){
    S += partials[b*2*C + c];
    Q += partials[b*2*C + C + c];
  }
  __shared__ float fs[1024], fq[1024];
  fs[t]=S; fq[t]=Q;
  __syncthreads();
  if(t < C){
    float St=fs[t], Qt=fq[t];
    for(int g=1; g<CH; g++){ St += fs[g*C+t]; Qt += fq[g*C+t]; }
    float m = St*invN;
    float var = fmaxf(Qt*invN - m*m, 0.f);
    float inv = rsqrtf(var + EPSV);
    float sc = gw[t]*inv;
    stats[t]   = sc;
    stats[C+t] = be[t] - m*sc;
  }
}

// ---------------- mean-pool per graph + linear head ----------------
__global__ __launch_bounds__(256) void k_pool(const float* __restrict__ A,
                                              const int* __restrict__ batch, int N,
                                              const float* __restrict__ Wc,
                                              const float* __restrict__ bc,
                                              float* __restrict__ out){
  int gId = blockIdx.x;
  int t = threadIdx.x;
  int lo=0, hi=N;
  while(lo<hi){ int mid=(lo+hi)>>1; if(batch[mid] < gId) lo=mid+1; else hi=mid; }
  int start = lo;
  lo=start; hi=N;
  while(lo<hi){ int mid=(lo+hi)>>1; if(batch[mid] < gId+1) lo=mid+1; else hi=mid; }
  int end = lo;

  int c = t & 63, rg = t >> 6;
  float s = 0.f;
  for(int r = start+rg; r < end; r += 4) s += A[(size_t)r*64 + c];
  __shared__ float ls[256];
  ls[t] = s;
  __syncthreads();
  if(t < 64){
    float tot = ls[t] + ls[64+t] + ls[128+t] + ls[192+t];
    float cnt = (float)(end - start);
    float mean = tot / fmaxf(cnt, 1.0f);
    float v = mean * Wc[t];
    #pragma unroll
    for(int o=32; o>0; o>>=1) v += __shfl_down(v, o, 64);
    if(t == 0) out[gId] = v + bc[0];
  }
}

// ---------------- host launch ----------------
extern "C" void kernel_launch(void* const* d_in, const int* in_sizes, int n_in,
                              void* d_out, int out_size, void* d_ws, size_t ws_size,
                              hipStream_t stream) {
  const float* x     = (const float*)d_in[0];
  const int*   ei    = (const int*)d_in[1];
  const int*   batch = (const int*)d_in[2];
  const float* W1 = (const float*)d_in[3];
  const float* b1 = (const float*)d_in[4];
  const float* g1 = (const float*)d_in[5];
  const float* be1= (const float*)d_in[6];
  const float* W2 = (const float*)d_in[7];
  const float* b2 = (const float*)d_in[8];
  const float* g2 = (const float*)d_in[9];
  const float* be2= (const float*)d_in[10];
  const float* W3 = (const float*)d_in[11];
  const float* b3 = (const float*)d_in[12];
  const float* Wc = (const float*)d_in[13];
  const float* bc = (const float*)d_in[14];

  int N = in_sizes[2];
  int E = in_sizes[1] / 2;
  int G = out_size;
  const int* srcp = ei;
  const int* dstp = ei + E;
  float* out = (float*)d_out;

  auto cdiv = [](long long a, long long b){ return (int)((a+b-1)/b); };
  int nbuk  = cdiv(N, NPB);             // 391 for N=100k (<= NBUK_MAX)
  int chunk = cdiv(E, EB);
  int L     = nbuk * EB;                // flat scan length
  int nbL   = cdiv(L, 1024);

  char* w = (char*)d_ws;
  float*    A        = (float*)w;    w += (size_t)N*64*4;
  unsigned* Pu       = (unsigned*)w; w += (size_t)N*32*4;   // bf16 P, N x 64
  float*    dis      = (float*)w;    w += (size_t)N*4;
  int*      row_ptr  = (int*)w;      w += (size_t)(N+1)*4;
  int*      csr_src  = (int*)w;      w += (size_t)E*4;
  uint2*    ebuf     = (uint2*)w;    w += (size_t)E*8;
  int*      cnt      = (int*)w;      w += (size_t)L*4;
  int*      pos      = (int*)w;      w += (size_t)L*4;
  int*      scan_loc = (int*)w;      w += (size_t)L*4;
  int*      scan_blk = (int*)w;      w += 1024*4;
  float*    partials = (float*)w;    w += (size_t)STATS_BLOCKS*128*4;
  float*    stats    = (float*)w;    w += 512;

  // ---- CSR build via two-level counting sort (no global atomics) ----
  k_csr_count<<<EB,256,0,stream>>>(dstp, E, chunk, nbuk, cnt);
  k_scan_local<<<nbL,1024,0,stream>>>(cnt, L, scan_loc, scan_blk);
  k_scan_sums<<<1,1024,0,stream>>>(scan_blk, nbL, row_ptr + N);   // total = E
  k_scan_add2<<<cdiv(L,256),256,0,stream>>>(scan_loc, scan_blk, L, pos);
  k_csr_scatter<<<EB,256,0,stream>>>(srcp, dstp, pos, E, chunk, nbuk, ebuf);
  k_csr_final<<<nbuk,256,0,stream>>>(ebuf, pos, nbuk, N, E, row_ptr, dis, csr_src);

  // ---- Layer 1: 32 -> 16 ----
  k_gemm1<<<cdiv(N,256),256,0,stream>>>(x, W1, dis, N, Pu);
  k_gather<16><<<cdiv((long long)N*2,256),256,0,stream>>>(row_ptr, csr_src, dis, Pu, b1, N, A);
  k_stats<16><<<STATS_BLOCKS,256,0,stream>>>(A, N, partials);
  k_bn_final<16><<<1,1024,0,stream>>>(partials, g1, be1, 1.0f/N, stats);

  // ---- Layer 2: 16 -> 64 (BN1 fused into GEMM staging) ----
  k_gemm_t<16><<<cdiv(N,128),256,0,stream>>>(A, W2, stats, dis, N, Pu);
  k_gather<64><<<cdiv((long long)N*8,256),256,0,stream>>>(row_ptr, csr_src, dis, Pu, b2, N, A);
  k_stats<64><<<STATS_BLOCKS,256,0,stream>>>(A, N, partials);
  k_bn_final<64><<<1,1024,0,stream>>>(partials, g2, be2, 1.0f/N, stats);

  // ---- Layer 3: 64 -> 64 (BN2 fused into GEMM staging) ----
  k_gemm_t<64><<<cdiv(N,128),256,0,stream>>>(A, W3, stats, dis, N, Pu);
  k_gather<64><<<cdiv((long long)N*8,256),256,0,stream>>>(row_ptr, csr_src, dis, Pu, b3, N, A);

  // ---- Pool + head ----
  k_pool<<<G,256,0,stream>>>(A, batch, N, Wc, bc, out);
}